// Round 3
// baseline (91.624 us; speedup 1.0000x reference)
//
#include <hip/hip_runtime.h>
#include <math.h>

#define NSEG 30          // scan steps i = 0..29
#define QOFF 0           // Q table: 31 entries * 6 floats
#define TOFF 192         // T table: 31 entries * 9 floats
#define TABSZ 472
#define PPT 8            // points per thread

typedef float vfloat4 __attribute__((ext_vector_type(4)));

__global__ __launch_bounds__(256) void yuksel_fused(
    const float* __restrict__ x, const float* __restrict__ P,
    float* __restrict__ out, int N)
{
    __shared__ float lt[TABSZ];
    const int tid = threadIdx.x;

    // ---- per-block table build: 5 independent column recurrences, lanes 0..4 ----
    if (tid < 5) {
        const int  col = tid;
        const bool isQ = col < 2;
        const int  tc  = col - 2;           // T-column index (valid when !isQ)

        float st0, st1, st2;
        if (isQ) {
            st0 = P[0*5+col]; st1 = P[1*5+col]; st2 = P[2*5+col];
        } else {
            float a0=P[0*5+2], b0=P[0*5+3], c0=P[0*5+4];
            float a1=P[1*5+2], b1=P[1*5+3], c1=P[1*5+4];
            float a2=P[2*5+2], b2=P[2*5+3], c2=P[2*5+4];
            st0 = (tc==0)? a0*a0+b0*b0 : (tc==1)? b0*(a0+c0) : b0*b0+c0*c0;
            st1 = (tc==0)? a1*a1+b1*b1 : (tc==1)? b1*(a1+c1) : b1*b1+c1*c1;
            st2 = (tc==0)? a2*a2+b2*b2 : (tc==1)? b2*(a2+c2) : b2*b2+c2*c2;
        }
        const int   stride = isQ ? 2 : 3;
        const int   entsz  = isQ ? 6 : 9;
        const int   boff   = isQ ? (QOFF + col) : (TOFF + tc);
        const float cA     = isQ ? 0.25f : 0.0625f;
        const float cB     = isQ ? 0.5f  : 0.25f;
        const float cC     = isQ ? 2.0f  : 4.0f;

        lt[boff + 0*stride] = st0;
        lt[boff + 1*stride] = st1;
        lt[boff + 2*stride] = st2;
        for (int i = 0; i < NSEG; ++i) {
            const int nr = i + 3;
            float nx;
            if (isQ) nx = P[nr*5+col];
            else {
                float a = P[nr*5+2], b = P[nr*5+3], c = P[nr*5+4];
                nx = (tc==0)? a*a+b*b : (tc==1)? b*(a+c) : b*b+c*c;
            }
            float n0 = (st0 + st2) * cA + st1 * cB;
            float n1 = cC * (st2 - (n0 + nx) * cA);
            st0 = n0; st1 = n1; st2 = nx;
            float* e = lt + boff + (i+1)*entsz;
            e[0*stride] = st0; e[1*stride] = st1; e[2*stride] = st2;
        }
    }
    __syncthreads();

    const float* lQ = lt + QOFF;
    const float* lT = lt + TOFF;

    const int gid = blockIdx.x * 256 + tid;
    const int j0  = gid * PPT;
    if (j0 >= N) return;

    float xs[PPT];
    {
        const vfloat4* xp = reinterpret_cast<const vfloat4*>(x + j0);
        vfloat4 xa = __builtin_nontemporal_load(xp);
        vfloat4 xb = __builtin_nontemporal_load(xp + 1);
        xs[0]=xa.x; xs[1]=xa.y; xs[2]=xa.z; xs[3]=xa.w;
        xs[4]=xb.x; xs[5]=xb.y; xs[6]=xb.z; xs[7]=xb.w;
    }

    float mu[2*PPT], sg[3*PPT];

#pragma unroll
    for (int q = 0; q < PPT; ++q) {
        float u  = xs[q] * 30.0f;
        float fi = floorf(u);
        fi = fminf(fmaxf(fi, 0.0f), 29.0f);
        int   i  = (int)fi;
        float d  = (u - fi) * 0.5f;          // in [0, 0.5)
        float e  = d + 0.5f;

        float omd = 1.0f - d;
        float bc0 = omd * omd, bc1 = 2.0f * d * omd, bc2 = d * d;
        float ome = 1.0f - e;
        float bp0 = ome * ome, bp1 = 2.0f * e * ome, bp2 = e * e;

        float cpi = cospif(d);
        float cw  = cpi * cpi;
        float sw  = 1.0f - cw;
        float cw2 = cw * cw, sw2 = sw * sw;

        const float* Qi = lQ + i * 6;    // Q_i (6) then Q_{i+1} (6)
        const float* Ti = lT + i * 9;    // T_i (9) then T_{i+1} (9)

        float fpx = bp0*Qi[0] + bp1*Qi[2] + bp2*Qi[4];
        float fpy = bp0*Qi[1] + bp1*Qi[3] + bp2*Qi[5];
        float fcx = bc0*Qi[6] + bc1*Qi[8] + bc2*Qi[10];
        float fcy = bc0*Qi[7] + bc1*Qi[9] + bc2*Qi[11];
        mu[2*q+0] = cw*fpx + sw*fcx;
        mu[2*q+1] = cw*fpy + sw*fcy;

        float a0 = bp0*bp0, a1 = bp1*bp1, a2 = bp2*bp2;
        float c0 = bc0*bc0, c1 = bc1*bc1, c2 = bc2*bc2;
        float gp0 = a0*Ti[0] + a1*Ti[3] + a2*Ti[6];
        float gp1 = a0*Ti[1] + a1*Ti[4] + a2*Ti[7];
        float gp2 = a0*Ti[2] + a1*Ti[5] + a2*Ti[8];
        float gc0 = c0*Ti[9]  + c1*Ti[12] + c2*Ti[15];
        float gc1 = c0*Ti[10] + c1*Ti[13] + c2*Ti[16];
        float gc2 = c0*Ti[11] + c1*Ti[14] + c2*Ti[17];
        sg[3*q+0] = cw2*gp0 + sw2*gc0;
        sg[3*q+1] = cw2*gp1 + sw2*gc1;
        sg[3*q+2] = cw2*gp2 + sw2*gc2;
    }

    // mu region: elements [2*j0, 2*j0+16) -> 4 aligned float4 nt-stores
    vfloat4* muOut = reinterpret_cast<vfloat4*>(out + 2*j0);
#pragma unroll
    for (int k = 0; k < PPT/2; ++k) {
        vfloat4 v = { mu[4*k], mu[4*k+1], mu[4*k+2], mu[4*k+3] };
        __builtin_nontemporal_store(v, muOut + k);
    }
    // sg region: elements [2N + 3*j0, +24) -> 6 aligned float4 nt-stores
    vfloat4* sgOut = reinterpret_cast<vfloat4*>(out + (size_t)2*N + 3*j0);
#pragma unroll
    for (int k = 0; k < (3*PPT)/4; ++k) {
        vfloat4 v = { sg[4*k], sg[4*k+1], sg[4*k+2], sg[4*k+3] };
        __builtin_nontemporal_store(v, sgOut + k);
    }
}

extern "C" void kernel_launch(void* const* d_in, const int* in_sizes, int n_in,
                              void* d_out, int out_size, void* d_ws, size_t ws_size,
                              hipStream_t stream) {
    const float* x = (const float*)d_in[0];
    const float* P = (const float*)d_in[1];
    float* out = (float*)d_out;
    int N = in_sizes[0];

    const int threads = 256;
    const int per_block = threads * PPT;
    int blocks = (N + per_block - 1) / per_block;
    yuksel_fused<<<blocks, threads, 0, stream>>>(x, P, out, N);
}

// Round 4
// 49.113 us; speedup vs baseline: 1.8656x; 1.8656x over previous
//
#include <hip/hip_runtime.h>
#include <math.h>

#define NSEG 30          // scan steps i = 0..29
#define QOFF 0           // Q table: 31 entries * 6 floats
#define TOFF 192         // T table: 31 entries * 9 floats
#define TABSZ 472
#define PPT 4            // points per thread

__global__ __launch_bounds__(256) void yuksel_fused(
    const float* __restrict__ x, const float* __restrict__ P,
    float* __restrict__ out, int N)
{
    __shared__ float lt[TABSZ];
    const int tid = threadIdx.x;

    // ---- per-block table build: 5 independent column recurrences, lanes 0..4 ----
    if (tid < 5) {
        const int  col = tid;
        const bool isQ = col < 2;
        const int  tc  = col - 2;           // T-column index (valid when !isQ)

        float st0, st1, st2;
        if (isQ) {
            st0 = P[0*5+col]; st1 = P[1*5+col]; st2 = P[2*5+col];
        } else {
            float a0=P[0*5+2], b0=P[0*5+3], c0=P[0*5+4];
            float a1=P[1*5+2], b1=P[1*5+3], c1=P[1*5+4];
            float a2=P[2*5+2], b2=P[2*5+3], c2=P[2*5+4];
            st0 = (tc==0)? a0*a0+b0*b0 : (tc==1)? b0*(a0+c0) : b0*b0+c0*c0;
            st1 = (tc==0)? a1*a1+b1*b1 : (tc==1)? b1*(a1+c1) : b1*b1+c1*c1;
            st2 = (tc==0)? a2*a2+b2*b2 : (tc==1)? b2*(a2+c2) : b2*b2+c2*c2;
        }
        const int   stride = isQ ? 2 : 3;
        const int   entsz  = isQ ? 6 : 9;
        const int   boff   = isQ ? (QOFF + col) : (TOFF + tc);
        const float cA     = isQ ? 0.25f : 0.0625f;
        const float cB     = isQ ? 0.5f  : 0.25f;
        const float cC     = isQ ? 2.0f  : 4.0f;

        lt[boff + 0*stride] = st0;
        lt[boff + 1*stride] = st1;
        lt[boff + 2*stride] = st2;
        for (int i = 0; i < NSEG; ++i) {
            const int nr = i + 3;
            float nx;
            if (isQ) nx = P[nr*5+col];
            else {
                float a = P[nr*5+2], b = P[nr*5+3], c = P[nr*5+4];
                nx = (tc==0)? a*a+b*b : (tc==1)? b*(a+c) : b*b+c*c;
            }
            float n0 = (st0 + st2) * cA + st1 * cB;
            float n1 = cC * (st2 - (n0 + nx) * cA);
            st0 = n0; st1 = n1; st2 = nx;
            float* e = lt + boff + (i+1)*entsz;
            e[0*stride] = st0; e[1*stride] = st1; e[2*stride] = st2;
        }
    }
    __syncthreads();

    const float* lQ = lt + QOFF;
    const float* lT = lt + TOFF;

    const int gid = blockIdx.x * 256 + tid;
    const int j0  = gid * PPT;
    if (j0 >= N) return;

    float4 xv = *reinterpret_cast<const float4*>(x + j0);
    float xs[PPT] = { xv.x, xv.y, xv.z, xv.w };
    float mu[2*PPT], sg[3*PPT];

#pragma unroll
    for (int q = 0; q < PPT; ++q) {
        float u  = xs[q] * 30.0f;
        float fi = floorf(u);
        fi = fminf(fmaxf(fi, 0.0f), 29.0f);
        int   i  = (int)fi;
        float d  = (u - fi) * 0.5f;          // in [0, 0.5)
        float e  = d + 0.5f;

        float omd = 1.0f - d;
        float bc0 = omd * omd, bc1 = 2.0f * d * omd, bc2 = d * d;
        float ome = 1.0f - e;
        float bp0 = ome * ome, bp1 = 2.0f * e * ome, bp2 = e * e;

        float cpi = cospif(d);
        float cw  = cpi * cpi;
        float sw  = 1.0f - cw;
        float cw2 = cw * cw, sw2 = sw * sw;

        const float* Qi = lQ + i * 6;    // Q_i (6) then Q_{i+1} (6)
        const float* Ti = lT + i * 9;    // T_i (9) then T_{i+1} (9)

        float fpx = bp0*Qi[0] + bp1*Qi[2] + bp2*Qi[4];
        float fpy = bp0*Qi[1] + bp1*Qi[3] + bp2*Qi[5];
        float fcx = bc0*Qi[6] + bc1*Qi[8] + bc2*Qi[10];
        float fcy = bc0*Qi[7] + bc1*Qi[9] + bc2*Qi[11];
        mu[2*q+0] = cw*fpx + sw*fcx;
        mu[2*q+1] = cw*fpy + sw*fcy;

        float a0 = bp0*bp0, a1 = bp1*bp1, a2 = bp2*bp2;
        float c0 = bc0*bc0, c1 = bc1*bc1, c2 = bc2*bc2;
        float gp0 = a0*Ti[0] + a1*Ti[3] + a2*Ti[6];
        float gp1 = a0*Ti[1] + a1*Ti[4] + a2*Ti[7];
        float gp2 = a0*Ti[2] + a1*Ti[5] + a2*Ti[8];
        float gc0 = c0*Ti[9]  + c1*Ti[12] + c2*Ti[15];
        float gc1 = c0*Ti[10] + c1*Ti[13] + c2*Ti[16];
        float gc2 = c0*Ti[11] + c1*Ti[14] + c2*Ti[17];
        sg[3*q+0] = cw2*gp0 + sw2*gc0;
        sg[3*q+1] = cw2*gp1 + sw2*gc1;
        sg[3*q+2] = cw2*gp2 + sw2*gc2;
    }

    // mu region: elements [2*j0, 2*j0+8) -> two aligned float4 stores
    float4* muOut = reinterpret_cast<float4*>(out + 2*j0);
    muOut[0] = make_float4(mu[0], mu[1], mu[2], mu[3]);
    muOut[1] = make_float4(mu[4], mu[5], mu[6], mu[7]);
    // sg region: elements [2N + 3*j0, +12) -> three aligned float4 stores
    float4* sgOut = reinterpret_cast<float4*>(out + (size_t)2*N + 3*j0);
    sgOut[0] = make_float4(sg[0], sg[1], sg[2],  sg[3]);
    sgOut[1] = make_float4(sg[4], sg[5], sg[6],  sg[7]);
    sgOut[2] = make_float4(sg[8], sg[9], sg[10], sg[11]);
}

extern "C" void kernel_launch(void* const* d_in, const int* in_sizes, int n_in,
                              void* d_out, int out_size, void* d_ws, size_t ws_size,
                              hipStream_t stream) {
    const float* x = (const float*)d_in[0];
    const float* P = (const float*)d_in[1];
    float* out = (float*)d_out;
    int N = in_sizes[0];

    const int threads = 256;
    const int per_block = threads * PPT;
    int blocks = (N + per_block - 1) / per_block;
    yuksel_fused<<<blocks, threads, 0, stream>>>(x, P, out, N);
}